// Round 1
// baseline (712.869 us; speedup 1.0000x reference)
//
#include <hip/hip_runtime.h>

#define HID 128
#define LDP 136   // padded LDS row stride in bf16 elems (272 B)

typedef short s16x8 __attribute__((ext_vector_type(8)));
typedef float f32x4 __attribute__((ext_vector_type(4)));
typedef float f32x2 __attribute__((ext_vector_type(2)));

__device__ __forceinline__ float bf2f(unsigned int u) {
  union { unsigned int i; float f; } v; v.i = u << 16; return v.f;
}
__device__ __forceinline__ float asf(unsigned int u) {
  union { unsigned int i; float f; } v; v.i = u; return v.f;
}
__device__ __forceinline__ unsigned short f2bf(float f) {
  union { float f; unsigned int i; } v; v.f = f;
  unsigned int r = v.i + 0x7fffu + ((v.i >> 16) & 1u);
  return (unsigned short)(r >> 16);
}
// f32 -> fp8 e4m3 byte (RNE, via HW cvt)
__device__ __forceinline__ unsigned char f2fp8(float f) {
  unsigned int p = __builtin_amdgcn_cvt_pk_fp8_f32(f, f, 0u, false);
  return (unsigned char)(p & 0xffu);
}

// ---------------- zero fill (vectorized) ----------------
__global__ void k_zero4(float4* __restrict__ p, size_t n4) {
  size_t i = (size_t)blockIdx.x * blockDim.x + threadIdx.x;
  if (i < n4) p[i] = (float4){0.f, 0.f, 0.f, 0.f};
}

// ---------------- counting sort ----------------
__global__ void k_hist(const int* __restrict__ dst, int* __restrict__ deg, int nE) {
  int e = blockIdx.x * blockDim.x + threadIdx.x;
  if (e < nE) atomicAdd(&deg[dst[e]], 1);
}

__global__ void k_scanA(const int* __restrict__ deg, int* __restrict__ bsum) {
  __shared__ int ss[256];
  int t = threadIdx.x;
  ss[t] = deg[blockIdx.x * 256 + t];
  __syncthreads();
  for (int off = 128; off; off >>= 1) {
    if (t < off) ss[t] += ss[t + off];
    __syncthreads();
  }
  if (t == 0) bsum[blockIdx.x] = ss[0];
}

__global__ void k_scanB(const int* __restrict__ bsum, int* __restrict__ bsumx, int NB) {
  __shared__ int sd[512];
  int t = threadIdx.x;
  int v = (t < NB) ? bsum[t] : 0;
  sd[t] = v;
  __syncthreads();
  for (int off = 1; off < 512; off <<= 1) {
    int a = (t >= off) ? sd[t - off] : 0;
    __syncthreads();
    sd[t] += a;
    __syncthreads();
  }
  if (t < NB) bsumx[t] = sd[t] - v;
}

// exclusive scan to BOTH cursor (mutated by scatter) and rowptr (kept)
__global__ void k_scanC(const int* __restrict__ deg, const int* __restrict__ bsumx,
                        int* __restrict__ cursor, int* __restrict__ rowptr) {
  __shared__ int ss[256];
  int t = threadIdx.x, i = blockIdx.x * 256 + t;
  int v = deg[i];
  ss[t] = v;
  __syncthreads();
  for (int off = 1; off < 256; off <<= 1) {
    int a = (t >= off) ? ss[t - off] : 0;
    __syncthreads();
    ss[t] += a;
    __syncthreads();
  }
  int ex = ss[t] - v + bsumx[blockIdx.x];
  cursor[i] = ex;
  rowptr[i] = ex;
}

// permute: only src and edge id (8 B random writes; ea gathered later from L3)
__global__ void k_scatter(const int* __restrict__ src, const int* __restrict__ dst,
                          int* __restrict__ cursor,
                          int* __restrict__ src_s, int* __restrict__ esort, int nE) {
  int e = blockIdx.x * blockDim.x + threadIdx.x;
  if (e >= nE) return;
  int d = dst[e];
  int pos = atomicAdd(&cursor[d], 1);
  src_s[pos] = src[e];
  esort[pos] = e;
}

// ---------------- transpose weights to bf16 ----------------
__global__ void k_prep_w(const float* __restrict__ ew2, const float* __restrict__ cw1,
                         const float* __restrict__ cw2, unsigned short* __restrict__ wT) {
  int idx = blockIdx.x * blockDim.x + threadIdx.x;
  if (idx >= 7 * 16384) return;
  int m = idx >> 14, i = idx & 16383;
  int n = i >> 7, k = i & 127;
  const float* s = (m == 0) ? ew2 : (m <= 3 ? cw1 + (size_t)(m - 1) * 16384
                                            : cw2 + (size_t)(m - 4) * 16384);
  wT[idx] = f2bf(s[k * 128 + n]);
}

// ---------------- node encoder ----------------
__global__ void k_node_enc(const float* __restrict__ x, const float* __restrict__ w,
                           const float* __restrict__ b, unsigned short* __restrict__ h16, int nN) {
  int idx = blockIdx.x * blockDim.x + threadIdx.x;
  if (idx >= nN * HID) return;
  int i = idx >> 7, j = idx & 127;
  float acc = b[j];
  const float* xr = x + (size_t)i * 7;
#pragma unroll
  for (int k = 0; k < 7; ++k) acc += xr[k] * w[k * HID + j];
  h16[idx] = f2bf(acc);
}

// ---------------- one-time edge encoder GEMM -> e8 (fp8, sorted order) ----------------
// gathers ea rows through esort (ea is L3-resident)
__global__ void __launch_bounds__(256) k_edge_gemm(
    const float* __restrict__ ea, const int* __restrict__ esort,
    const float* __restrict__ ew1, const float* __restrict__ eb1,
    const unsigned short* __restrict__ w2t, const float* __restrict__ eb2,
    unsigned char* __restrict__ e8, int nE) {
  __shared__ __attribute__((aligned(16))) unsigned short ts1[128 * LDP];
  __shared__ float eaL[384];
  __shared__ int esL[128];
  int tid = threadIdx.x;
  int e0 = blockIdx.x * 128;                      // nE % 128 == 0
  if (tid < 128) esL[tid] = esort[e0 + tid];
  __syncthreads();
  for (int i = tid; i < 384; i += 256) {
    int r = i / 3, c = i - r * 3;
    eaL[i] = ea[(size_t)esL[r] * 3 + c];
  }
  __syncthreads();
  {
    int j = tid & 127, r0 = (tid >> 7) * 64;
    float wa = ew1[j], wb = ew1[HID + j], wc = ew1[2 * HID + j], bj = eb1[j];
    for (int r = r0; r < r0 + 64; ++r) {
      float a = bj + eaL[r * 3] * wa + eaL[r * 3 + 1] * wb + eaL[r * 3 + 2] * wc;
      ts1[r * LDP + j] = f2bf(fmaxf(a, 0.f));
    }
  }
  __syncthreads();
  int wave = tid >> 6, lane = tid & 63;
  int l15 = lane & 15, quad = lane >> 4;
  int rbase = (wave >> 1) * 64, nbase = (wave & 1) * 64;
  f32x4 acc[4][4];
#pragma unroll
  for (int i = 0; i < 4; ++i)
#pragma unroll
    for (int j = 0; j < 4; ++j) acc[i][j] = (f32x4){0.f, 0.f, 0.f, 0.f};
  for (int kc = 0; kc < 4; ++kc) {
    int k0 = kc * 32 + quad * 8;
    s16x8 af[4], bf[4];
#pragma unroll
    for (int t = 0; t < 4; ++t)
      af[t] = *(const s16x8*)&ts1[(rbase + t * 16 + l15) * LDP + k0];
#pragma unroll
    for (int t = 0; t < 4; ++t)
      bf[t] = *(const s16x8*)&w2t[(size_t)(nbase + t * 16 + l15) * HID + k0];
#pragma unroll
    for (int i = 0; i < 4; ++i)
#pragma unroll
      for (int j = 0; j < 4; ++j)
        acc[i][j] = __builtin_amdgcn_mfma_f32_16x16x32_bf16(af[i], bf[j], acc[i][j], 0, 0, 0);
  }
  float ebv[4];
#pragma unroll
  for (int t = 0; t < 4; ++t) ebv[t] = eb2[nbase + t * 16 + l15];
#pragma unroll
  for (int tr = 0; tr < 4; ++tr)
#pragma unroll
    for (int reg = 0; reg < 4; ++reg) {
      int row = rbase + tr * 16 + quad * 4 + reg;   // C/D: col=lane&15, row=quad*4+reg
#pragma unroll
      for (int tc = 0; tc < 4; ++tc) {
        int col = nbase + tc * 16 + l15;
        e8[(size_t)(e0 + row) * HID + col] = f2fp8(acc[tr][tc][reg] + ebv[tc]);
      }
    }
}

// ---------------- fused CSR-aggregate + conv MLP, 32-node tile ----------------
// phase A (rewritten): 1 edge per step across the FULL wave; lane owns cols
//   (2*lane, 2*lane+1) exclusively -> no cross-lane reduction at node end.
//   All CSR control is wave-uniform scalar (readfirstlane'd rowptr); pipeline:
//   h/e loads 1 edge ahead, src_s 3 edges ahead, rolling re/reN rowptr prefetch.
//   e8 loads nontemporal so the 82 MB stream doesn't evict h (25.6 MB) from L2.
__global__ void __launch_bounds__(256) k_conv_csr(
    const unsigned short* __restrict__ h16in, const unsigned char* __restrict__ e8,
    const int* __restrict__ src_s, const int* __restrict__ rowptr,
    const unsigned short* __restrict__ w1t, const float* __restrict__ b1,
    const unsigned short* __restrict__ w2t, const float* __restrict__ b2,
    unsigned short* __restrict__ h16out, int nN) {
  __shared__ __attribute__((aligned(16))) unsigned short zs[32 * LDP];
  int tid = threadIdx.x;
  int n0 = blockIdx.x * 32;
  int wave = tid >> 6, lane = tid & 63;
  int l15 = lane & 15, quad = lane >> 4;
  int waveu = __builtin_amdgcn_readfirstlane(wave);
  int c2 = lane * 2;                                // 2 cols per lane, 64*2 = 128
  // ---------- phase A ----------
  {
    int nodeBase = n0 + waveu * 8;                  // scalar
    // stage the 8 own-node h rows into zs (dword per lane, coalesced 256 B)
#pragma unroll
    for (int i = 0; i < 8; ++i) {
      int n = nodeBase + i; if (n > nN - 1) n = nN - 1;
      unsigned int hv = *(const unsigned int*)&h16in[(size_t)n * HID + c2];
      *(unsigned int*)&zs[(waveu * 8 + i) * LDP + c2] = hv;
    }
    int i0 = nodeBase;     if (i0 > nN) i0 = nN;
    int i1 = nodeBase + 1; if (i1 > nN) i1 = nN;
    int i2 = nodeBase + 2; if (i2 > nN) i2 = nN;
    int i8 = nodeBase + 8; if (i8 > nN) i8 = nN;
    int gb   = __builtin_amdgcn_readfirstlane(rowptr[i0]);
    int gEnd = __builtin_amdgcn_readfirstlane(rowptr[i8]);
    int re   = __builtin_amdgcn_readfirstlane(rowptr[i1]);
    int reN  = __builtin_amdgcn_readfirstlane(rowptr[i2]);
    float a0 = 0.f, a1 = 0.f;
    int ni = 0;
#define FLUSH_NODE(NI)                                                      \
    { int zr = (waveu * 8 + (NI)) * LDP + c2;                               \
      unsigned int z = *(const unsigned int*)&zs[zr];                       \
      float z0 = asf(z << 16) + a0;                                         \
      float z1 = asf(z & 0xffff0000u) + a1;                                 \
      *(unsigned int*)&zs[zr] = (unsigned int)f2bf(z0) |                    \
                                ((unsigned int)f2bf(z1) << 16);             \
      a0 = 0.f; a1 = 0.f; }
    if (gb < gEnd) {
      int gL = gEnd - 1;
      // pipeline prologue
      int s0 = src_s[gb];
      int j1 = gb + 1 > gL ? gL : gb + 1;
      int j2 = gb + 2 > gL ? gL : gb + 2;
      int j3 = gb + 3 > gL ? gL : gb + 3;
      int s1v = src_s[j1];
      int s2v = src_s[j2];
      int s3v = src_s[j3];
      unsigned int hA = *(const unsigned int*)&h16in[(size_t)s0 * HID + c2];
      unsigned int eA = __builtin_nontemporal_load(
          (const unsigned short*)&e8[(size_t)gb * HID + c2]);
      for (int e = gb; e < gEnd; ++e) {
        // issue loads for edge e+1 (h,e) and src for edge e+4
        int j4 = e + 4 > gL ? gL : e + 4;
        int s4v = src_s[j4];
        int ip = e + 1 > gL ? gL : e + 1;
        unsigned int hB = *(const unsigned int*)&h16in[(size_t)s1v * HID + c2];
        unsigned int eB = __builtin_nontemporal_load(
            (const unsigned short*)&e8[(size_t)ip * HID + c2]);
        // node-boundary flush (wave-uniform scalar control)
        while (ni < 8 && re <= e) {
          FLUSH_NODE(ni)
          ++ni;
          re = reN;
          int jn = nodeBase + ni + 2; if (jn > nN) jn = nN;
          reN = __builtin_amdgcn_readfirstlane(rowptr[jn]);
        }
        // process edge e: acc += relu(h_src + e) on this lane's 2 cols
        f32x2 pe = __builtin_amdgcn_cvt_pk_f32_fp8(eA, false);
        float h0 = asf(hA << 16);
        float h1 = asf(hA & 0xffff0000u);
        a0 += fmaxf(h0 + pe[0], 0.f);
        a1 += fmaxf(h1 + pe[1], 0.f);
        hA = hB; eA = eB; s1v = s2v; s2v = s3v; s3v = s4v;
      }
    }
    while (ni < 8) { FLUSH_NODE(ni) ++ni; }
#undef FLUSH_NODE
  }
  __syncthreads();
  // ---------- phase B: z @ w1 + b1, relu -> zs ----------
  int rbase = (wave >> 1) * 16, nbase = (wave & 1) * 64;
  f32x4 acc[4];
#pragma unroll
  for (int j = 0; j < 4; ++j) acc[j] = (f32x4){0.f, 0.f, 0.f, 0.f};
  for (int kc = 0; kc < 4; ++kc) {
    int k0 = kc * 32 + quad * 8;
    s16x8 af, bf[4];
    af = *(const s16x8*)&zs[(rbase + l15) * LDP + k0];
#pragma unroll
    for (int t = 0; t < 4; ++t)
      bf[t] = *(const s16x8*)&w1t[(size_t)(nbase + t * 16 + l15) * HID + k0];
#pragma unroll
    for (int j = 0; j < 4; ++j)
      acc[j] = __builtin_amdgcn_mfma_f32_16x16x32_bf16(af, bf[j], acc[j], 0, 0, 0);
  }
  __syncthreads();
  {
    float bv[4];
#pragma unroll
    for (int t = 0; t < 4; ++t) bv[t] = b1[nbase + t * 16 + l15];
#pragma unroll
    for (int tc = 0; tc < 4; ++tc)
#pragma unroll
      for (int reg = 0; reg < 4; ++reg) {
        int row = rbase + quad * 4 + reg;
        int col = nbase + tc * 16 + l15;
        zs[row * LDP + col] = f2bf(fmaxf(acc[tc][reg] + bv[tc], 0.f));
      }
  }
  __syncthreads();
  // ---------- phase C: @ w2 + b2, relu -> h16out ----------
#pragma unroll
  for (int j = 0; j < 4; ++j) acc[j] = (f32x4){0.f, 0.f, 0.f, 0.f};
  for (int kc = 0; kc < 4; ++kc) {
    int k0 = kc * 32 + quad * 8;
    s16x8 af, bf[4];
    af = *(const s16x8*)&zs[(rbase + l15) * LDP + k0];
#pragma unroll
    for (int t = 0; t < 4; ++t)
      bf[t] = *(const s16x8*)&w2t[(size_t)(nbase + t * 16 + l15) * HID + k0];
#pragma unroll
    for (int j = 0; j < 4; ++j)
      acc[j] = __builtin_amdgcn_mfma_f32_16x16x32_bf16(af, bf[j], acc[j], 0, 0, 0);
  }
  {
    float bv[4];
#pragma unroll
    for (int t = 0; t < 4; ++t) bv[t] = b2[nbase + t * 16 + l15];
#pragma unroll
    for (int reg = 0; reg < 4; ++reg) {
      int grow = n0 + rbase + quad * 4 + reg;
      if (grow < nN) {
#pragma unroll
        for (int tc = 0; tc < 4; ++tc) {
          int col = nbase + tc * 16 + l15;
          h16out[(size_t)grow * HID + col] = f2bf(fmaxf(acc[tc][reg] + bv[tc], 0.f));
        }
      }
    }
  }
}

// ---------------- counts ----------------
__global__ void k_counts(const int* __restrict__ batch, int* __restrict__ cnts, int nN) {
  int i = blockIdx.x * blockDim.x + threadIdx.x;
  if (i < nN) atomicAdd(&cnts[batch[i]], 1);
}

// ---------------- segment-reduced pool (batch sorted) ----------------
__global__ void __launch_bounds__(256) k_pool2(
    const unsigned short* __restrict__ h16, const int* __restrict__ batch,
    float* __restrict__ g, int nN) {
  __shared__ int bL[128];
  int tid = threadIdx.x;
  int n0 = blockIdx.x * 128;
  if (tid < 128) {
    int n = n0 + tid;
    bL[tid] = (n < nN) ? batch[n] : -1;
  }
  __syncthreads();
  int half = tid >> 7, col = tid & 127;
  int rs = half * 64;
  int cur = -1;
  float s = 0.f;
  for (int r = rs; r < rs + 64; ++r) {
    int b = bL[r];
    float v = (b >= 0) ? bf2f((unsigned int)h16[(size_t)(n0 + r) * HID + col]) : 0.f;
    if (b != cur) {
      if (cur >= 0) atomicAdd(&g[(size_t)cur * HID + col], s);
      cur = b; s = v;
    } else s += v;
  }
  if (cur >= 0) atomicAdd(&g[(size_t)cur * HID + col], s);
}

// ---------------- heads ----------------
__global__ void __launch_bounds__(128) k_head(
    const float* __restrict__ g, const int* __restrict__ counts,
    const float* __restrict__ clw1, const float* __restrict__ clb1,
    const float* __restrict__ clw2, const float* __restrict__ clb2,
    const float* __restrict__ rw1, const float* __restrict__ rb1,
    const float* __restrict__ rw2, const float* __restrict__ rb2,
    float* __restrict__ out, int nG) {
  __shared__ float gs[HID];
  int b = blockIdx.x;
  int tid = threadIdx.x;
  float cnt = fmaxf((float)counts[b], 1.f);
  gs[tid] = g[b * HID + tid] / cnt;
  __syncthreads();
  int wave = tid >> 6, lane = tid & 63;
  const float* w1 = wave ? rw1 : clw1;
  const float* b1 = wave ? rb1 : clb1;
  const float* w2 = wave ? rw2 : clw2;
  const float* b2 = wave ? rb2 : clb2;
  float acc = b1[lane];
  for (int k = 0; k < HID; ++k) acc += gs[k] * w1[k * 64 + lane];
  acc = fmaxf(acc, 0.f) * w2[lane];
#pragma unroll
  for (int off = 32; off; off >>= 1) acc += __shfl_down(acc, off);
  if (lane == 0) out[wave * nG + b] = acc + b2[0];
}

extern "C" void kernel_launch(void* const* d_in, const int* in_sizes, int n_in,
                              void* d_out, int out_size, void* d_ws, size_t ws_size,
                              hipStream_t stream) {
  const float* x      = (const float*)d_in[0];
  const float* ea     = (const float*)d_in[1];
  const int*   eidx   = (const int*)d_in[2];
  const int*   batch  = (const int*)d_in[3];
  const float* node_w = (const float*)d_in[4];
  const float* node_b = (const float*)d_in[5];
  const float* ew1    = (const float*)d_in[6];
  const float* eb1    = (const float*)d_in[7];
  const float* ew2    = (const float*)d_in[8];
  const float* eb2    = (const float*)d_in[9];
  const float* cw1    = (const float*)d_in[10];
  const float* cb1    = (const float*)d_in[11];
  const float* cw2    = (const float*)d_in[12];
  const float* cb2    = (const float*)d_in[13];
  const float* clw1   = (const float*)d_in[14];
  const float* clb1   = (const float*)d_in[15];
  const float* clw2   = (const float*)d_in[16];
  const float* clb2   = (const float*)d_in[17];
  const float* rw1    = (const float*)d_in[18];
  const float* rb1    = (const float*)d_in[19];
  const float* rw2    = (const float*)d_in[20];
  const float* rb2    = (const float*)d_in[21];
  float* out = (float*)d_out;

  int nN = in_sizes[3];        // 100000
  int nE = in_sizes[2] / 2;    // 640000 (divisible by 128)
  int nG = out_size / 2;       // 2048
  const int* src = eidx;
  const int* dst = eidx + nE;

  int NB = (nN + 255) / 256;
  int bins = NB * 256;

  // ---- workspace (~140 MB) ----
  size_t hN = (size_t)nN * HID;
  size_t gN = (size_t)nG * HID;
  float* g    = (float*)d_ws;                       // gN
  int*   cnts = (int*)(g + gN);                     // nG
  unsigned short* wT   = (unsigned short*)(cnts + nG);  // 7*16384
  unsigned short* h16a = wT + 7 * 16384;            // hN
  unsigned short* h16b = h16a + hN;                 // hN
  int* deg    = (int*)(h16b + hN);                  // bins
  int* cursor = deg + bins;                         // bins
  int* rowptr = cursor + bins;                      // bins
  int* bsum   = rowptr + bins;                      // 512
  int* bsumx  = bsum + 512;                         // 512
  int* src_s  = bsumx + 512;                        // nE
  int* esort  = src_s + nE;                         // nE
  unsigned char* e8 = (unsigned char*)(esort + nE); // nE*128 fp8

  // ---- counting sort of edges by dst (builds CSR rowptr + permutation) ----
  k_zero4<<<(int)((bins / 4 + 255) / 256), 256, 0, stream>>>((float4*)deg, bins / 4);
  k_hist<<<(nE + 255) / 256, 256, 0, stream>>>(dst, deg, nE);
  k_scanA<<<NB, 256, 0, stream>>>(deg, bsum);
  k_scanB<<<1, 512, 0, stream>>>(bsum, bsumx, NB);
  k_scanC<<<NB, 256, 0, stream>>>(deg, bsumx, cursor, rowptr);
  k_scatter<<<(nE + 255) / 256, 256, 0, stream>>>(src, dst, cursor, src_s, esort, nE);

  k_prep_w<<<(7 * 16384 + 255) / 256, 256, 0, stream>>>(ew2, cw1, cw2, wT);
  k_edge_gemm<<<nE / 128, 256, 0, stream>>>(ea, esort, ew1, eb1, wT, eb2, e8, nE);
  k_node_enc<<<(nN * HID + 255) / 256, 256, 0, stream>>>(x, node_w, node_b, h16a, nN);

  // ping-pong: A->B, B->A, A->B  (final in h16b)
  unsigned short* hin  = h16a;
  unsigned short* hout = h16b;
  for (int l = 0; l < 3; ++l) {
    k_conv_csr<<<(nN + 31) / 32, 256, 0, stream>>>(
        hin, e8, src_s, rowptr,
        wT + (size_t)(1 + l) * 16384, cb1 + (size_t)l * HID,
        wT + (size_t)(4 + l) * 16384, cb2 + (size_t)l * HID, hout, nN);
    unsigned short* t = hin; hin = hout; hout = t;
  }

  k_zero4<<<(int)(((gN + nG) / 4 + 255) / 256), 256, 0, stream>>>((float4*)g, (gN + nG) / 4);
  k_counts<<<(nN + 255) / 256, 256, 0, stream>>>(batch, cnts, nN);
  k_pool2<<<(nN + 127) / 128, 256, 0, stream>>>(hin, batch, g, nN);
  k_head<<<nG, 128, 0, stream>>>(g, cnts, clw1, clb1, clw2, clb2,
                                 rw1, rb1, rw2, rb2, out, nG);
}

// Round 2
// 616.690 us; speedup vs baseline: 1.1560x; 1.1560x over previous
//
#include <hip/hip_runtime.h>

#define HID 128
#define LDP 136   // padded LDS row stride in bf16 elems (272 B)

typedef short s16x8 __attribute__((ext_vector_type(8)));
typedef float f32x4 __attribute__((ext_vector_type(4)));
typedef float f32x2 __attribute__((ext_vector_type(2)));

__device__ __forceinline__ float bf2f(unsigned int u) {
  union { unsigned int i; float f; } v; v.i = u << 16; return v.f;
}
__device__ __forceinline__ float asf(unsigned int u) {
  union { unsigned int i; float f; } v; v.i = u; return v.f;
}
__device__ __forceinline__ unsigned short f2bf(float f) {
  union { float f; unsigned int i; } v; v.f = f;
  unsigned int r = v.i + 0x7fffu + ((v.i >> 16) & 1u);
  return (unsigned short)(r >> 16);
}
// f32 -> fp8 e4m3 byte (RNE, via HW cvt)
__device__ __forceinline__ unsigned char f2fp8(float f) {
  unsigned int p = __builtin_amdgcn_cvt_pk_fp8_f32(f, f, 0u, false);
  return (unsigned char)(p & 0xffu);
}

// ---------------- zero fill (vectorized) ----------------
__global__ void k_zero4(float4* __restrict__ p, size_t n4) {
  size_t i = (size_t)blockIdx.x * blockDim.x + threadIdx.x;
  if (i < n4) p[i] = (float4){0.f, 0.f, 0.f, 0.f};
}

// ---------------- counting sort ----------------
__global__ void k_hist(const int* __restrict__ dst, int* __restrict__ deg, int nE) {
  int e = blockIdx.x * blockDim.x + threadIdx.x;
  if (e < nE) atomicAdd(&deg[dst[e]], 1);
}

__global__ void k_scanA(const int* __restrict__ deg, int* __restrict__ bsum) {
  __shared__ int ss[256];
  int t = threadIdx.x;
  ss[t] = deg[blockIdx.x * 256 + t];
  __syncthreads();
  for (int off = 128; off; off >>= 1) {
    if (t < off) ss[t] += ss[t + off];
    __syncthreads();
  }
  if (t == 0) bsum[blockIdx.x] = ss[0];
}

__global__ void k_scanB(const int* __restrict__ bsum, int* __restrict__ bsumx, int NB) {
  __shared__ int sd[512];
  int t = threadIdx.x;
  int v = (t < NB) ? bsum[t] : 0;
  sd[t] = v;
  __syncthreads();
  for (int off = 1; off < 512; off <<= 1) {
    int a = (t >= off) ? sd[t - off] : 0;
    __syncthreads();
    sd[t] += a;
    __syncthreads();
  }
  if (t < NB) bsumx[t] = sd[t] - v;
}

// exclusive scan to BOTH cursor (mutated by scatter) and rowptr (kept)
__global__ void k_scanC(const int* __restrict__ deg, const int* __restrict__ bsumx,
                        int* __restrict__ cursor, int* __restrict__ rowptr) {
  __shared__ int ss[256];
  int t = threadIdx.x, i = blockIdx.x * 256 + t;
  int v = deg[i];
  ss[t] = v;
  __syncthreads();
  for (int off = 1; off < 256; off <<= 1) {
    int a = (t >= off) ? ss[t - off] : 0;
    __syncthreads();
    ss[t] += a;
    __syncthreads();
  }
  int ex = ss[t] - v + bsumx[blockIdx.x];
  cursor[i] = ex;
  rowptr[i] = ex;
}

// ---- group-count scan (ngrp = ceil(deg/4)) -> gptr ----
__global__ void k_gscanA(const int* __restrict__ deg, int* __restrict__ bsum) {
  __shared__ int ss[256];
  int t = threadIdx.x;
  ss[t] = (deg[blockIdx.x * 256 + t] + 3) >> 2;
  __syncthreads();
  for (int off = 128; off; off >>= 1) {
    if (t < off) ss[t] += ss[t + off];
    __syncthreads();
  }
  if (t == 0) bsum[blockIdx.x] = ss[0];
}

__global__ void k_gscanC(const int* __restrict__ deg, const int* __restrict__ bsumx,
                         int* __restrict__ gptr) {
  __shared__ int ss[256];
  int t = threadIdx.x, i = blockIdx.x * 256 + t;
  int v = (deg[i] + 3) >> 2;
  ss[t] = v;
  __syncthreads();
  for (int off = 1; off < 256; off <<= 1) {
    int a = (t >= off) ? ss[t - off] : 0;
    __syncthreads();
    ss[t] += a;
    __syncthreads();
  }
  gptr[i] = ss[t] - v + bsumx[blockIdx.x];
}

// ---- per-group metadata: {ebase:20 | row5:20..24 | (cnt-1):25..26 | flush:27} ----
__global__ void k_fill_grp(const int* __restrict__ rowptr, const int* __restrict__ gptr,
                           int* __restrict__ grp, int nN) {
  int n = blockIdx.x * blockDim.x + threadIdx.x;
  if (n >= nN) return;
  int rb = rowptr[n], re = rowptr[n + 1], g = gptr[n];
  int row = (n & 31) << 20;
  for (int e = rb; e < re; e += 4, ++g) {
    int cnt = re - e; if (cnt > 4) cnt = 4;
    grp[g] = e | row | ((cnt - 1) << 25) | ((e + 4 >= re) ? (1 << 27) : 0);
  }
}

// permute: only src and edge id (8 B random writes; ea gathered later from L3)
__global__ void k_scatter(const int* __restrict__ src, const int* __restrict__ dst,
                          int* __restrict__ cursor,
                          int* __restrict__ src_s, int* __restrict__ esort, int nE) {
  int e = blockIdx.x * blockDim.x + threadIdx.x;
  if (e >= nE) return;
  int d = dst[e];
  int pos = atomicAdd(&cursor[d], 1);
  src_s[pos] = src[e];
  esort[pos] = e;
}

// ---------------- transpose weights to bf16 ----------------
__global__ void k_prep_w(const float* __restrict__ ew2, const float* __restrict__ cw1,
                         const float* __restrict__ cw2, unsigned short* __restrict__ wT) {
  int idx = blockIdx.x * blockDim.x + threadIdx.x;
  if (idx >= 7 * 16384) return;
  int m = idx >> 14, i = idx & 16383;
  int n = i >> 7, k = i & 127;
  const float* s = (m == 0) ? ew2 : (m <= 3 ? cw1 + (size_t)(m - 1) * 16384
                                            : cw2 + (size_t)(m - 4) * 16384);
  wT[idx] = f2bf(s[k * 128 + n]);
}

// ---------------- node encoder ----------------
__global__ void k_node_enc(const float* __restrict__ x, const float* __restrict__ w,
                           const float* __restrict__ b, unsigned short* __restrict__ h16, int nN) {
  int idx = blockIdx.x * blockDim.x + threadIdx.x;
  if (idx >= nN * HID) return;
  int i = idx >> 7, j = idx & 127;
  float acc = b[j];
  const float* xr = x + (size_t)i * 7;
#pragma unroll
  for (int k = 0; k < 7; ++k) acc += xr[k] * w[k * HID + j];
  h16[idx] = f2bf(acc);
}

// ---------------- one-time edge encoder GEMM -> e8 (fp8, sorted order) ----------------
// gathers ea rows through esort (ea is L3-resident)
__global__ void __launch_bounds__(256) k_edge_gemm(
    const float* __restrict__ ea, const int* __restrict__ esort,
    const float* __restrict__ ew1, const float* __restrict__ eb1,
    const unsigned short* __restrict__ w2t, const float* __restrict__ eb2,
    unsigned char* __restrict__ e8, int nE) {
  __shared__ __attribute__((aligned(16))) unsigned short ts1[128 * LDP];
  __shared__ float eaL[384];
  __shared__ int esL[128];
  int tid = threadIdx.x;
  int e0 = blockIdx.x * 128;                      // nE % 128 == 0
  if (tid < 128) esL[tid] = esort[e0 + tid];
  __syncthreads();
  for (int i = tid; i < 384; i += 256) {
    int r = i / 3, c = i - r * 3;
    eaL[i] = ea[(size_t)esL[r] * 3 + c];
  }
  __syncthreads();
  {
    int j = tid & 127, r0 = (tid >> 7) * 64;
    float wa = ew1[j], wb = ew1[HID + j], wc = ew1[2 * HID + j], bj = eb1[j];
    for (int r = r0; r < r0 + 64; ++r) {
      float a = bj + eaL[r * 3] * wa + eaL[r * 3 + 1] * wb + eaL[r * 3 + 2] * wc;
      ts1[r * LDP + j] = f2bf(fmaxf(a, 0.f));
    }
  }
  __syncthreads();
  int wave = tid >> 6, lane = tid & 63;
  int l15 = lane & 15, quad = lane >> 4;
  int rbase = (wave >> 1) * 64, nbase = (wave & 1) * 64;
  f32x4 acc[4][4];
#pragma unroll
  for (int i = 0; i < 4; ++i)
#pragma unroll
    for (int j = 0; j < 4; ++j) acc[i][j] = (f32x4){0.f, 0.f, 0.f, 0.f};
  for (int kc = 0; kc < 4; ++kc) {
    int k0 = kc * 32 + quad * 8;
    s16x8 af[4], bf[4];
#pragma unroll
    for (int t = 0; t < 4; ++t)
      af[t] = *(const s16x8*)&ts1[(rbase + t * 16 + l15) * LDP + k0];
#pragma unroll
    for (int t = 0; t < 4; ++t)
      bf[t] = *(const s16x8*)&w2t[(size_t)(nbase + t * 16 + l15) * HID + k0];
#pragma unroll
    for (int i = 0; i < 4; ++i)
#pragma unroll
      for (int j = 0; j < 4; ++j)
        acc[i][j] = __builtin_amdgcn_mfma_f32_16x16x32_bf16(af[i], bf[j], acc[i][j], 0, 0, 0);
  }
  float ebv[4];
#pragma unroll
  for (int t = 0; t < 4; ++t) ebv[t] = eb2[nbase + t * 16 + l15];
#pragma unroll
  for (int tr = 0; tr < 4; ++tr)
#pragma unroll
    for (int reg = 0; reg < 4; ++reg) {
      int row = rbase + tr * 16 + quad * 4 + reg;   // C/D: col=lane&15, row=quad*4+reg
#pragma unroll
      for (int tc = 0; tc < 4; ++tc) {
        int col = nbase + tc * 16 + l15;
        e8[(size_t)(e0 + row) * HID + col] = f2fp8(acc[tr][tc][reg] + ebv[tc]);
      }
    }
}

// ---------------- fused CSR-aggregate + conv MLP, 32-node tile ----------------
// phase A: quad q owns edge (ebase+q) of a node-aligned 4-edge group; lane covers
//   8 cols (e via 8B fp8 NT load, h via 16B bf16). ALL group control is a
//   precomputed packed int (grp[]): {ebase:20|row:5|cnt-1:2|flush:1}, decoded
//   on the SALU via readfirstlane. 3-stage pipeline: S(meta+src) -> L(e,h) -> F.
//   Node-end: shfl_xor butterfly + quad-0 b128 RMW into zs (bf16).
__global__ void __launch_bounds__(256) k_conv_csr(
    const unsigned short* __restrict__ h16in, const unsigned char* __restrict__ e8,
    const int* __restrict__ src_s, const int* __restrict__ gptr,
    const int* __restrict__ grp,
    const unsigned short* __restrict__ w1t, const float* __restrict__ b1,
    const unsigned short* __restrict__ w2t, const float* __restrict__ b2,
    unsigned short* __restrict__ h16out, int nN, int nE) {
  __shared__ __attribute__((aligned(16))) unsigned short zs[32 * LDP];
  int tid = threadIdx.x;
  int n0 = blockIdx.x * 32;
  int wave = tid >> 6, lane = tid & 63;
  int l15 = lane & 15, quad = lane >> 4;
  int c16 = l15 * 8;
  // ---------- phase A ----------
  {
    int waveu = __builtin_amdgcn_readfirstlane(wave);
    int wbase = waveu * 8;
    int nodeBase = n0 + wbase;
    // stage the 8 own-node h rows into zs (2 x uint4 per lane)
#pragma unroll
    for (int i = 0; i < 2; ++i) {
      int r = i * 4 + quad;
      int n = nodeBase + r; if (n > nN - 1) n = nN - 1;
      *(uint4*)&zs[(wbase + r) * LDP + c16] =
          *(const uint4*)&h16in[(size_t)n * HID + c16];
    }
    int gb = __builtin_amdgcn_readfirstlane(gptr[nodeBase]);
    int gE = __builtin_amdgcn_readfirstlane(gptr[nodeBase + 8]);
    float acc[8];
#pragma unroll
    for (int j = 0; j < 8; ++j) acc[j] = 0.f;

#define SSTAGE(M, SV, gg)                                          \
    { M = __builtin_amdgcn_readfirstlane(grp[gg]);                 \
      int eix = (M & 0xFFFFF) + quad;                              \
      if (eix > nE - 1) eix = nE - 1;                              \
      SV = src_s[eix]; }
#define LSTAGE(M, SV, EV, HV)                                      \
    { int eix = (M & 0xFFFFF) + quad;                              \
      if (eix > nE - 1) eix = nE - 1;                              \
      EV = __builtin_nontemporal_load(                             \
          (const unsigned long long*)&e8[(size_t)eix * HID + c16]);\
      HV = *(const uint4*)&h16in[(size_t)SV * HID + c16]; }

    int mA = 0, mB = 0, svA = 0, svB = 0;
    unsigned long long evA = 0, evB = 0;
    uint4 hvA = {0, 0, 0, 0}, hvB = {0, 0, 0, 0};
    bool aA = (gb < gE), aB = (gb + 1 < gE);
    if (aA) SSTAGE(mA, svA, gb)
    if (aB) SSTAGE(mB, svB, gb + 1)
    if (aA) LSTAGE(mA, svA, evA, hvA)
    int g = gb;
    while (aA) {
      bool aC = (g + 2 < gE);
      int mC = 0, svC = 0;
      if (aC) SSTAGE(mC, svC, g + 2)
      if (aB) LSTAGE(mB, svB, evB, hvB)
      // fold edge group g
      {
        int cnt = (mA >> 25) & 3;
        if (quad <= cnt) {
          unsigned int e0w = (unsigned int)evA, e1w = (unsigned int)(evA >> 32);
          const unsigned int* hw = (const unsigned int*)&hvA;
          f32x2 pa = __builtin_amdgcn_cvt_pk_f32_fp8(e0w, false);
          f32x2 pb = __builtin_amdgcn_cvt_pk_f32_fp8(e0w, true);
          f32x2 pc = __builtin_amdgcn_cvt_pk_f32_fp8(e1w, false);
          f32x2 pd = __builtin_amdgcn_cvt_pk_f32_fp8(e1w, true);
          acc[0] += fmaxf(asf(hw[0] << 16) + pa[0], 0.f);
          acc[1] += fmaxf(asf(hw[0] & 0xffff0000u) + pa[1], 0.f);
          acc[2] += fmaxf(asf(hw[1] << 16) + pb[0], 0.f);
          acc[3] += fmaxf(asf(hw[1] & 0xffff0000u) + pb[1], 0.f);
          acc[4] += fmaxf(asf(hw[2] << 16) + pc[0], 0.f);
          acc[5] += fmaxf(asf(hw[2] & 0xffff0000u) + pc[1], 0.f);
          acc[6] += fmaxf(asf(hw[3] << 16) + pd[0], 0.f);
          acc[7] += fmaxf(asf(hw[3] & 0xffff0000u) + pd[1], 0.f);
        }
        if (mA & (1 << 27)) {   // last group of its node: reduce + RMW
#pragma unroll
          for (int j = 0; j < 8; ++j) {
            acc[j] += __shfl_xor(acc[j], 16);
            acc[j] += __shfl_xor(acc[j], 32);
          }
          if (quad == 0) {
            int zr = ((mA >> 20) & 31) * LDP + c16;
            uint4 z = *(const uint4*)&zs[zr];
            unsigned int* zw = (unsigned int*)&z;
#pragma unroll
            for (int j = 0; j < 4; ++j) {
              float z0 = asf(zw[j] << 16) + acc[2 * j];
              float z1 = asf(zw[j] & 0xffff0000u) + acc[2 * j + 1];
              zw[j] = (unsigned int)f2bf(z0) | ((unsigned int)f2bf(z1) << 16);
            }
            *(uint4*)&zs[zr] = z;
          }
#pragma unroll
          for (int j = 0; j < 8; ++j) acc[j] = 0.f;
        }
      }
      mA = mB; svA = svB; evA = evB; hvA = hvB; aA = aB;
      mB = mC; svB = svC; aB = aC;
      ++g;
    }
#undef SSTAGE
#undef LSTAGE
  }
  __syncthreads();
  // ---------- phase B: z @ w1 + b1, relu -> zs ----------
  int rbase = (wave >> 1) * 16, nbase = (wave & 1) * 64;
  f32x4 acc[4];
#pragma unroll
  for (int j = 0; j < 4; ++j) acc[j] = (f32x4){0.f, 0.f, 0.f, 0.f};
  for (int kc = 0; kc < 4; ++kc) {
    int k0 = kc * 32 + quad * 8;
    s16x8 af, bf[4];
    af = *(const s16x8*)&zs[(rbase + l15) * LDP + k0];
#pragma unroll
    for (int t = 0; t < 4; ++t)
      bf[t] = *(const s16x8*)&w1t[(size_t)(nbase + t * 16 + l15) * HID + k0];
#pragma unroll
    for (int j = 0; j < 4; ++j)
      acc[j] = __builtin_amdgcn_mfma_f32_16x16x32_bf16(af, bf[j], acc[j], 0, 0, 0);
  }
  __syncthreads();
  {
    float bv[4];
#pragma unroll
    for (int t = 0; t < 4; ++t) bv[t] = b1[nbase + t * 16 + l15];
#pragma unroll
    for (int tc = 0; tc < 4; ++tc)
#pragma unroll
      for (int reg = 0; reg < 4; ++reg) {
        int row = rbase + quad * 4 + reg;
        int col = nbase + tc * 16 + l15;
        zs[row * LDP + col] = f2bf(fmaxf(acc[tc][reg] + bv[tc], 0.f));
      }
  }
  __syncthreads();
  // ---------- phase C: @ w2 + b2, relu -> h16out ----------
#pragma unroll
  for (int j = 0; j < 4; ++j) acc[j] = (f32x4){0.f, 0.f, 0.f, 0.f};
  for (int kc = 0; kc < 4; ++kc) {
    int k0 = kc * 32 + quad * 8;
    s16x8 af, bf[4];
    af = *(const s16x8*)&zs[(rbase + l15) * LDP + k0];
#pragma unroll
    for (int t = 0; t < 4; ++t)
      bf[t] = *(const s16x8*)&w2t[(size_t)(nbase + t * 16 + l15) * HID + k0];
#pragma unroll
    for (int j = 0; j < 4; ++j)
      acc[j] = __builtin_amdgcn_mfma_f32_16x16x32_bf16(af, bf[j], acc[j], 0, 0, 0);
  }
  {
    float bv[4];
#pragma unroll
    for (int t = 0; t < 4; ++t) bv[t] = b2[nbase + t * 16 + l15];
#pragma unroll
    for (int reg = 0; reg < 4; ++reg) {
      int grow = n0 + rbase + quad * 4 + reg;
      if (grow < nN) {
#pragma unroll
        for (int tc = 0; tc < 4; ++tc) {
          int col = nbase + tc * 16 + l15;
          h16out[(size_t)grow * HID + col] = f2bf(fmaxf(acc[tc][reg] + bv[tc], 0.f));
        }
      }
    }
  }
}

// ---------------- counts ----------------
__global__ void k_counts(const int* __restrict__ batch, int* __restrict__ cnts, int nN) {
  int i = blockIdx.x * blockDim.x + threadIdx.x;
  if (i < nN) atomicAdd(&cnts[batch[i]], 1);
}

// ---------------- segment-reduced pool (batch sorted) ----------------
__global__ void __launch_bounds__(256) k_pool2(
    const unsigned short* __restrict__ h16, const int* __restrict__ batch,
    float* __restrict__ g, int nN) {
  __shared__ int bL[128];
  int tid = threadIdx.x;
  int n0 = blockIdx.x * 128;
  if (tid < 128) {
    int n = n0 + tid;
    bL[tid] = (n < nN) ? batch[n] : -1;
  }
  __syncthreads();
  int half = tid >> 7, col = tid & 127;
  int rs = half * 64;
  int cur = -1;
  float s = 0.f;
  for (int r = rs; r < rs + 64; ++r) {
    int b = bL[r];
    float v = (b >= 0) ? bf2f((unsigned int)h16[(size_t)(n0 + r) * HID + col]) : 0.f;
    if (b != cur) {
      if (cur >= 0) atomicAdd(&g[(size_t)cur * HID + col], s);
      cur = b; s = v;
    } else s += v;
  }
  if (cur >= 0) atomicAdd(&g[(size_t)cur * HID + col], s);
}

// ---------------- heads ----------------
__global__ void __launch_bounds__(128) k_head(
    const float* __restrict__ g, const int* __restrict__ counts,
    const float* __restrict__ clw1, const float* __restrict__ clb1,
    const float* __restrict__ clw2, const float* __restrict__ clb2,
    const float* __restrict__ rw1, const float* __restrict__ rb1,
    const float* __restrict__ rw2, const float* __restrict__ rb2,
    float* __restrict__ out, int nG) {
  __shared__ float gs[HID];
  int b = blockIdx.x;
  int tid = threadIdx.x;
  float cnt = fmaxf((float)counts[b], 1.f);
  gs[tid] = g[b * HID + tid] / cnt;
  __syncthreads();
  int wave = tid >> 6, lane = tid & 63;
  const float* w1 = wave ? rw1 : clw1;
  const float* b1 = wave ? rb1 : clb1;
  const float* w2 = wave ? rw2 : clw2;
  const float* b2 = wave ? rb2 : clb2;
  float acc = b1[lane];
  for (int k = 0; k < HID; ++k) acc += gs[k] * w1[k * 64 + lane];
  acc = fmaxf(acc, 0.f) * w2[lane];
#pragma unroll
  for (int off = 32; off; off >>= 1) acc += __shfl_down(acc, off);
  if (lane == 0) out[wave * nG + b] = acc + b2[0];
}

extern "C" void kernel_launch(void* const* d_in, const int* in_sizes, int n_in,
                              void* d_out, int out_size, void* d_ws, size_t ws_size,
                              hipStream_t stream) {
  const float* x      = (const float*)d_in[0];
  const float* ea     = (const float*)d_in[1];
  const int*   eidx   = (const int*)d_in[2];
  const int*   batch  = (const int*)d_in[3];
  const float* node_w = (const float*)d_in[4];
  const float* node_b = (const float*)d_in[5];
  const float* ew1    = (const float*)d_in[6];
  const float* eb1    = (const float*)d_in[7];
  const float* ew2    = (const float*)d_in[8];
  const float* eb2    = (const float*)d_in[9];
  const float* cw1    = (const float*)d_in[10];
  const float* cb1    = (const float*)d_in[11];
  const float* cw2    = (const float*)d_in[12];
  const float* cb2    = (const float*)d_in[13];
  const float* clw1   = (const float*)d_in[14];
  const float* clb1   = (const float*)d_in[15];
  const float* clw2   = (const float*)d_in[16];
  const float* clb2   = (const float*)d_in[17];
  const float* rw1    = (const float*)d_in[18];
  const float* rb1    = (const float*)d_in[19];
  const float* rw2    = (const float*)d_in[20];
  const float* rb2    = (const float*)d_in[21];
  float* out = (float*)d_out;

  int nN = in_sizes[3];        // 100000
  int nE = in_sizes[2] / 2;    // 640000 (divisible by 128)
  int nG = out_size / 2;       // 2048
  const int* src = eidx;
  const int* dst = eidx + nE;

  int NB = (nN + 255) / 256;
  int bins = NB * 256;

  // ---- workspace (~144 MB) ----
  size_t hN = (size_t)nN * HID;
  size_t gN = (size_t)nG * HID;
  float* g    = (float*)d_ws;                       // gN
  int*   cnts = (int*)(g + gN);                     // nG
  unsigned short* wT   = (unsigned short*)(cnts + nG);  // 7*16384
  unsigned short* h16a = wT + 7 * 16384;            // hN
  unsigned short* h16b = h16a + hN;                 // hN
  int* deg    = (int*)(h16b + hN);                  // bins
  int* cursor = deg + bins;                         // bins
  int* rowptr = cursor + bins;                      // bins
  int* gptr   = rowptr + bins;                      // bins
  int* bsum   = gptr + bins;                        // 512
  int* bsumx  = bsum + 512;                         // 512
  int* gbsum  = bsumx + 512;                        // 512
  int* gbsumx = gbsum + 512;                        // 512
  int* src_s  = gbsumx + 512;                       // nE
  int* esort  = src_s + nE;                         // nE
  int* grp    = esort + nE;                         // <= nE/4 + nN + pad
  unsigned char* e8 = (unsigned char*)(grp + (nE / 4 + nN + 256)); // nE*128 fp8

  // ---- counting sort of edges by dst (builds CSR rowptr + permutation) ----
  k_zero4<<<(int)((bins / 4 + 255) / 256), 256, 0, stream>>>((float4*)deg, bins / 4);
  k_hist<<<(nE + 255) / 256, 256, 0, stream>>>(dst, deg, nE);
  k_scanA<<<NB, 256, 0, stream>>>(deg, bsum);
  k_scanB<<<1, 512, 0, stream>>>(bsum, bsumx, NB);
  k_scanC<<<NB, 256, 0, stream>>>(deg, bsumx, cursor, rowptr);
  k_scatter<<<(nE + 255) / 256, 256, 0, stream>>>(src, dst, cursor, src_s, esort, nE);

  // ---- group plan (node-aligned 4-edge groups, shared by all 3 conv layers) ----
  k_gscanA<<<NB, 256, 0, stream>>>(deg, gbsum);
  k_scanB<<<1, 512, 0, stream>>>(gbsum, gbsumx, NB);
  k_gscanC<<<NB, 256, 0, stream>>>(deg, gbsumx, gptr);
  k_fill_grp<<<(nN + 255) / 256, 256, 0, stream>>>(rowptr, gptr, grp, nN);

  k_prep_w<<<(7 * 16384 + 255) / 256, 256, 0, stream>>>(ew2, cw1, cw2, wT);
  k_edge_gemm<<<nE / 128, 256, 0, stream>>>(ea, esort, ew1, eb1, wT, eb2, e8, nE);
  k_node_enc<<<(nN * HID + 255) / 256, 256, 0, stream>>>(x, node_w, node_b, h16a, nN);

  // ping-pong: A->B, B->A, A->B  (final in h16b)
  unsigned short* hin  = h16a;
  unsigned short* hout = h16b;
  for (int l = 0; l < 3; ++l) {
    k_conv_csr<<<(nN + 31) / 32, 256, 0, stream>>>(
        hin, e8, src_s, gptr, grp,
        wT + (size_t)(1 + l) * 16384, cb1 + (size_t)l * HID,
        wT + (size_t)(4 + l) * 16384, cb2 + (size_t)l * HID, hout, nN, nE);
    unsigned short* t = hin; hin = hout; hout = t;
  }

  k_zero4<<<(int)(((gN + nG) / 4 + 255) / 256), 256, 0, stream>>>((float4*)g, (gN + nG) / 4);
  k_counts<<<(nN + 255) / 256, 256, 0, stream>>>(batch, cnts, nN);
  k_pool2<<<(nN + 127) / 128, 256, 0, stream>>>(hin, batch, g, nN);
  k_head<<<nG, 128, 0, stream>>>(g, cnts, clw1, clb1, clw2, clb2,
                                 rw1, rb1, rw2, rb2, out, nG);
}